// Round 3
// baseline (146.545 us; speedup 1.0000x reference)
//
#include <hip/hip_runtime.h>

#define N_TERMS 2048
#define NCOL 4096
#define NC4 1024                           // float4 per row
#define NCHUNK 128
#define RPC (N_TERMS / NCHUNK)             // 16 rows per chunk

typedef float f4_t __attribute__((ext_vector_type(4)));

// ---------------------------------------------------------------------------
// Kernel 1 (block-partitioned fusion of two independent jobs):
//   blocks 0..511    : partial column |x| sums over row chunks (bitwise-
//                      identical mapping to the verified round-0 kernel).
//   blocks 512..2559 : zero-fill the 4096 tail rows of out (67 MB). These have
//                      NO data dependency, so they stream concurrently with
//                      the x read instead of serializing behind stats.
// The ~2048 nonzero tail entries are scattered later by k_stats' last block.
// ---------------------------------------------------------------------------
__global__ void k_pass1(const float* __restrict__ x, float* __restrict__ partial,
                        float* __restrict__ out, int* __restrict__ done_ctr) {
    const int b = blockIdx.x;
    const int t = threadIdx.x;
    if (b < 512) {
        if (b == 0 && t == 0) *done_ctr = 0;   // ws is poisoned between runs
        const int col4 = (b & 3) * 256 + t;    // [0, 1024)
        const int chunk = b >> 2;              // [0, 128)
        int r0 = chunk * RPC;
        const int r1 = r0 + RPC;
        if (r0 == 0) r0 = 1;                   // center row excluded
        const f4_t* x4 = (const f4_t*)x;
        f4_t acc = {0.f, 0.f, 0.f, 0.f};
#pragma unroll
        for (int r = r0; r < r1; ++r) {
            f4_t v = x4[(long)r * NC4 + col4];
            acc.x += fabsf(v.x);
            acc.y += fabsf(v.y);
            acc.z += fabsf(v.z);
            acc.w += fabsf(v.w);
        }
        ((f4_t*)partial)[chunk * NC4 + col4] = acc;
    } else {
        // zero tail rows 2048..6143: 4096*1024 f4 slots, 2048 blocks x 256 thr
        // x 8 f4 each; every wave store is a contiguous coalesced line.
        const int zb = b - 512;                // [0, 2048)
        f4_t* o4 = (f4_t*)out;
        const long base4 = (long)N_TERMS * NC4 + (long)zb * 2048;
        const f4_t z = {0.f, 0.f, 0.f, 0.f};
#pragma unroll
        for (int i = 0; i < 8; ++i)
            __builtin_nontemporal_store(z, &o4[base4 + i * 256 + t]);
    }
}

// ---------------------------------------------------------------------------
// Kernel 2: per-column stats (identical math/order to the verified version:
// absmax must stay 0.0) PLUS last-block prefix scan, PLUS direct scatter of
// the nonzero tail entries into the (already zeroed) tail region: one 4-byte
// store per crossing column (~2048 total) replaces the old 67 MB tail pass.
// ---------------------------------------------------------------------------
__global__ void k_stats(const float* __restrict__ x, const float* __restrict__ partial,
                        float* __restrict__ out, float* __restrict__ scale,
                        float* __restrict__ dhalf, int* __restrict__ crossflag,
                        int* __restrict__ done_ctr) {
    const int t = threadIdx.x;
    const int lane = t & 63;        // column within block's 64-col slice
    const int q = t >> 6;           // which quarter of the 128 chunks
    const int c = blockIdx.x * 64 + lane;

    float s0 = 0.f, s1 = 0.f, s2 = 0.f, s3 = 0.f;
    const int k0 = q * 32;
#pragma unroll 8
    for (int k = 0; k < 32; k += 4) {
        s0 += partial[(k0 + k + 0) * NCOL + c];
        s1 += partial[(k0 + k + 1) * NCOL + c];
        s2 += partial[(k0 + k + 2) * NCOL + c];
        s3 += partial[(k0 + k + 3) * NCOL + c];
    }
    __shared__ float red[4][64];
    red[q][lane] = (s0 + s1) + (s2 + s3);
    __syncthreads();
    if (q == 0) {
        float s = (red[0][lane] + red[1][lane]) + (red[2][lane] + red[3][lane]);
        float x0 = x[c];
        float u = x0 + s;
        float l = x0 - s;
        bool cross = (l * u) < 0.0f;
        bool pos = (l >= 0.0f);
        float denom = u - l;
        float lam = (pos ? 1.0f : 0.0f) +
                    (cross ? ((denom != 0.0f) ? u / denom : 0.5f) : 0.0f);
        float delta = fmaxf(-lam * l, (1.0f - lam) * u);
        float crossf = cross ? 1.0f : 0.0f;
        float posf = pos ? 1.0f : 0.0f;
        out[c] = (delta * 0.5f + lam * x0) * crossf + x0 * posf;  // output row 0
        scale[c] = lam * crossf + posf;
        dhalf[c] = delta * 0.5f * crossf;
        crossflag[c] = cross ? 1 : 0;
    }

    // ---- last block: exclusive prefix sum + direct tail scatter -----------
    __threadfence();  // release: crossflag/dhalf visible device-wide
    __shared__ int is_last;
    if (t == 0) is_last = (atomicAdd(done_ctr, 1) == (int)gridDim.x - 1);
    __syncthreads();
    if (!is_last) return;
    __threadfence();  // acquire: see all blocks' crossflag/dhalf writes

    const int T = 256;
    const int PER = NCOL / T;  // 16
    __shared__ int tsum[T];
    const int base = t * PER;
    int cf[PER];
    int ex[PER];
    int run = 0;
#pragma unroll
    for (int i = 0; i < PER; ++i) {
        cf[i] = crossflag[base + i];
        ex[i] = run;
        run += cf[i];
    }
    tsum[t] = run;
    __syncthreads();
    for (int off = 1; off < T; off <<= 1) {
        int v = 0;
        if (t >= off) v = tsum[t - off];
        __syncthreads();
        tsum[t] += v;
        __syncthreads();
    }
    const int excl = (t == 0) ? 0 : tsum[t - 1];
#pragma unroll
    for (int i = 0; i < PER; ++i) {
        if (cf[i]) {
            const int c2 = base + i;
            const long row = N_TERMS + excl + ex[i];
            out[row * (long)NCOL + c2] = dhalf[c2];  // tail already zeroed by k_pass1
        }
    }
}

// ---------------------------------------------------------------------------
// Kernel 3: gens rows 1..2047 only (x * scale[col]); x is L3-resident from
// pass 1. 4 rows per thread at a fixed col4; every store 1 KiB coalesced.
// ---------------------------------------------------------------------------
__global__ void k_gens(const float* __restrict__ x, const float* __restrict__ scale,
                       float* __restrict__ out) {
    const int g = blockIdx.x * blockDim.x + threadIdx.x;  // [0, 524288)
    const int col4 = g & 1023;
    const int group = g >> 10;        // [0, 512)
    const int r0 = group << 2;
    const f4_t* x4 = (const f4_t*)x;
    f4_t* o4 = (f4_t*)out;
    const f4_t sc = ((const f4_t*)scale)[col4];

    if (group == 0) {
#pragma unroll
        for (int r = 1; r < 4; ++r) {
            f4_t v = x4[(long)r * NC4 + col4] * sc;
            __builtin_nontemporal_store(v, &o4[(long)r * NC4 + col4]);
        }
    } else {
#pragma unroll
        for (int i = 0; i < 4; ++i) {
            const int r = r0 + i;
            f4_t v = x4[(long)r * NC4 + col4] * sc;
            __builtin_nontemporal_store(v, &o4[(long)r * NC4 + col4]);
        }
    }
}

extern "C" void kernel_launch(void* const* d_in, const int* in_sizes, int n_in,
                              void* d_out, int out_size, void* d_ws, size_t ws_size,
                              hipStream_t stream) {
    const float* x = (const float*)d_in[0];
    float* out = (float*)d_out;

    float* ws = (float*)d_ws;
    float* partial   = ws;                       // 128*4096 floats = 2 MB
    float* scale     = partial + NCHUNK * NCOL;  // 4096 floats
    float* dhalf     = scale + NCOL;             // 4096 floats
    int*   crossflag = (int*)(dhalf + NCOL);     // 4096 ints
    int*   done_ctr  = crossflag + NCOL;         // 1 int

    k_pass1<<<2560, 256, 0, stream>>>(x, partial, out, done_ctr);
    k_stats<<<64, 256, 0, stream>>>(x, partial, out, scale, dhalf, crossflag, done_ctr);
    k_gens<<<2048, 256, 0, stream>>>(x, scale, out);
}

// Round 4
// 137.124 us; speedup vs baseline: 1.0687x; 1.0687x over previous
//
#include <hip/hip_runtime.h>

#define N_TERMS 2048
#define NCOL 4096
#define NC4 1024                           // float4 per row
#define NCHUNK 128
#define RPC (N_TERMS / NCHUNK)             // 16 rows per chunk

typedef float f4_t __attribute__((ext_vector_type(4)));

// ---------------------------------------------------------------------------
// Kernel 1: pure x-read -> partial column |x| sums (bitwise-identical mapping
// to the verified round-0 kernel). Nothing competes with this read: it gates
// the whole downstream chain, so it runs alone at read BW (~5.3 us).
// ---------------------------------------------------------------------------
__global__ void k_partial_abs(const float* __restrict__ x, float* __restrict__ partial) {
    int col4 = blockIdx.x * blockDim.x + threadIdx.x;  // [0, 1024)
    int chunk = blockIdx.y;
    int r0 = chunk * RPC;
    int r1 = r0 + RPC;
    if (r0 == 0) r0 = 1;  // center row excluded from abs_sum
    const f4_t* x4 = (const f4_t*)x;
    f4_t acc = {0.f, 0.f, 0.f, 0.f};
#pragma unroll
    for (int r = r0; r < r1; ++r) {
        f4_t v = x4[(long)r * NC4 + col4];
        acc.x += fabsf(v.x);
        acc.y += fabsf(v.y);
        acc.z += fabsf(v.z);
        acc.w += fabsf(v.w);
    }
    ((f4_t*)partial)[chunk * NC4 + col4] = acc;
}

// ---------------------------------------------------------------------------
// Kernel 2 (block-partitioned): blocks 0..63 run the verified per-column
// stats (identical math/order: absmax must stay 0.0); blocks 64..575 zero the
// 67 MB tail region. The stats latency (~3 us, BW-idle) hides entirely under
// the zero-write stream instead of occupying its own serial slot.
// ---------------------------------------------------------------------------
__global__ void k_stats_zero(const float* __restrict__ x, const float* __restrict__ partial,
                             float* __restrict__ out, float* __restrict__ scale,
                             float* __restrict__ dhalf, int* __restrict__ crossflag) {
    const int b = blockIdx.x;
    const int t = threadIdx.x;

    if (b < 64) {
        const int lane = t & 63;        // column within block's 64-col slice
        const int q = t >> 6;           // which quarter of the 128 chunks
        const int c = b * 64 + lane;

        float s0 = 0.f, s1 = 0.f, s2 = 0.f, s3 = 0.f;
        const int k0 = q * 32;
#pragma unroll 8
        for (int k = 0; k < 32; k += 4) {
            s0 += partial[(k0 + k + 0) * NCOL + c];
            s1 += partial[(k0 + k + 1) * NCOL + c];
            s2 += partial[(k0 + k + 2) * NCOL + c];
            s3 += partial[(k0 + k + 3) * NCOL + c];
        }
        __shared__ float red[4][64];
        red[q][lane] = (s0 + s1) + (s2 + s3);
        __syncthreads();
        if (q == 0) {
            float s = (red[0][lane] + red[1][lane]) + (red[2][lane] + red[3][lane]);
            float x0 = x[c];
            float u = x0 + s;
            float l = x0 - s;
            bool cross = (l * u) < 0.0f;
            bool pos = (l >= 0.0f);
            float denom = u - l;
            float lam = (pos ? 1.0f : 0.0f) +
                        (cross ? ((denom != 0.0f) ? u / denom : 0.5f) : 0.0f);
            float delta = fmaxf(-lam * l, (1.0f - lam) * u);
            float crossf = cross ? 1.0f : 0.0f;
            float posf = pos ? 1.0f : 0.0f;
            out[c] = (delta * 0.5f + lam * x0) * crossf + x0 * posf;  // output row 0
            scale[c] = lam * crossf + posf;
            dhalf[c] = delta * 0.5f * crossf;
            crossflag[c] = cross ? 1 : 0;
        }
    } else {
        // zero tail rows 2048..6143: 512 blocks x 256 thr x 32 f4 = 67.1 MB,
        // every wave store a contiguous coalesced 4 KB line per unroll step.
        const int zb = b - 64;                 // [0, 512)
        f4_t* o4 = (f4_t*)out;
        const long base4 = (long)N_TERMS * NC4 + (long)zb * 8192;
        const f4_t z = {0.f, 0.f, 0.f, 0.f};
#pragma unroll
        for (int i = 0; i < 32; ++i)
            __builtin_nontemporal_store(z, &o4[base4 + i * 256 + t]);
    }
}

// ---------------------------------------------------------------------------
// Kernel 3: gens rows 1..2047 (x * scale[col]; x is L3-resident) across
// blocks 0..2047, plus ONE extra block (2048) doing the 4096-wide prefix scan
// and scattering the ~2048 nonzero dhalf values into the (already-zeroed)
// tail. The scan+scatter (~1.5 us) hides under the 67 MB gens stream; no
// atomics, no device fences, no rowtarget array.
// ---------------------------------------------------------------------------
__global__ void k_gens_scatter(const float* __restrict__ x, const float* __restrict__ scale,
                               const float* __restrict__ dhalf,
                               const int* __restrict__ crossflag,
                               float* __restrict__ out) {
    const int b = blockIdx.x;
    const int t = threadIdx.x;
    if (b < 2048) {
        const int g = b * 256 + t;        // [0, 524288)
        const int col4 = g & 1023;
        const int group = g >> 10;        // [0, 512)
        const int r0 = group << 2;
        const f4_t* x4 = (const f4_t*)x;
        f4_t* o4 = (f4_t*)out;
        const f4_t sc = ((const f4_t*)scale)[col4];

        if (group == 0) {
#pragma unroll
            for (int r = 1; r < 4; ++r) {
                f4_t v = x4[(long)r * NC4 + col4] * sc;
                __builtin_nontemporal_store(v, &o4[(long)r * NC4 + col4]);
            }
        } else {
#pragma unroll
            for (int i = 0; i < 4; ++i) {
                const int r = r0 + i;
                f4_t v = x4[(long)r * NC4 + col4] * sc;
                __builtin_nontemporal_store(v, &o4[(long)r * NC4 + col4]);
            }
        }
    } else {
        // exclusive prefix sum of crossflag + direct scatter (integer-exact)
        const int T = 256;
        const int PER = NCOL / T;  // 16
        __shared__ int tsum[T];
        const int base = t * PER;
        int cf[PER];
        int ex[PER];
        int run = 0;
#pragma unroll
        for (int i = 0; i < PER; ++i) {
            cf[i] = crossflag[base + i];
            ex[i] = run;
            run += cf[i];
        }
        tsum[t] = run;
        __syncthreads();
        for (int off = 1; off < T; off <<= 1) {
            int v = 0;
            if (t >= off) v = tsum[t - off];
            __syncthreads();
            tsum[t] += v;
            __syncthreads();
        }
        const int excl = (t == 0) ? 0 : tsum[t - 1];
#pragma unroll
        for (int i = 0; i < PER; ++i) {
            if (cf[i]) {
                const int c = base + i;
                const long row = N_TERMS + excl + ex[i];
                out[row * (long)NCOL + c] = dhalf[c];  // tail zeroed by k_stats_zero
            }
        }
    }
}

extern "C" void kernel_launch(void* const* d_in, const int* in_sizes, int n_in,
                              void* d_out, int out_size, void* d_ws, size_t ws_size,
                              hipStream_t stream) {
    const float* x = (const float*)d_in[0];
    float* out = (float*)d_out;

    float* ws = (float*)d_ws;
    float* partial   = ws;                       // 128*4096 floats = 2 MB
    float* scale     = partial + NCHUNK * NCOL;  // 4096 floats
    float* dhalf     = scale + NCOL;             // 4096 floats
    int*   crossflag = (int*)(dhalf + NCOL);     // 4096 ints

    k_partial_abs<<<dim3(NC4 / 256, NCHUNK), 256, 0, stream>>>(x, partial);
    k_stats_zero<<<576, 256, 0, stream>>>(x, partial, out, scale, dhalf, crossflag);
    k_gens_scatter<<<2049, 256, 0, stream>>>(x, scale, dhalf, crossflag, out);
}